// Round 4
// baseline (185.403 us; speedup 1.0000x reference)
//
#include <hip/hip_runtime.h>
#include <hip/hip_cooperative_groups.h>
#include <math.h>

namespace cg = cooperative_groups;

#define GN 8192
#define GF 64
#define GFIN 256
#define NEG 0.2f
#define NBLK 256
#define TPB 512
#define NCH 2048
#define CHSZ 4    // GN / NCH

// workspace layout in floats
#define OFF_WH   0
#define OFF_S1   (GN*GF)
#define OFF_S2   (OFF_S1 + GN)
#define OFF_ZS   (OFF_S2 + GN)
#define OFF_IDX  (OFF_ZS + GN)              // int32
#define OFF_CHA  (OFF_IDX + GN)             // NCH*GF
#define OFF_CHB  (OFF_CHA + NCH*GF)
#define OFF_SCA  (OFF_CHB + NCH*GF)         // NCH
#define OFF_SCB  (OFF_SCA + NCH)
#define OFF_OFA  (OFF_SCB + NCH)            // (NCH+1)*GF
#define OFF_OFB  (OFF_OFA + (NCH+1)*GF)
#define OFF_OSA  (OFF_OFB + (NCH+1)*GF)     // NCH+1
#define OFF_OSB  (OFF_OSA + (NCH+1))

// Single cooperative kernel: 256 blocks (1/CU) x 512 threads (8 waves).
// LDS (64KB static) is time-shared across phases:
//   ph1: W [16384 floats] | ph2: s2 copy [8192] | ph3-5: zs [8192] + scan wred [8192..8215]
__global__ __launch_bounds__(TPB) void k_gat(
        const float* __restrict__ h, const float* __restrict__ W,
        const float* __restrict__ a, float* __restrict__ wsf,
        float* __restrict__ out) {
    cg::grid_group grid = cg::this_grid();
    __shared__ float lds[GFIN*GF];           // 64 KB

    float* Wh  = wsf + OFF_WH;
    float* s1  = wsf + OFF_S1;
    float* s2  = wsf + OFF_S2;
    float* zs  = wsf + OFF_ZS;
    int*   idx = (int*)(wsf + OFF_IDX);
    float* chA = wsf + OFF_CHA;
    float* chB = wsf + OFF_CHB;
    float* scA = wsf + OFF_SCA;
    float* scB = wsf + OFF_SCB;
    float* ofA = wsf + OFF_OFA;
    float* ofB = wsf + OFF_OFB;
    float* osA = wsf + OFF_OSA;
    float* osB = wsf + OFF_OSB;

    int t = threadIdx.x, lane = t & 63;
    int b = blockIdx.x;

    // ================= phase 1: Wh = h@W, s1 = Wh@a1, s2 = Wh@a2 =============
    {
        const float4* W4 = (const float4*)W;
        float4* l4 = (float4*)lds;
        #pragma unroll
        for (int m = 0; m < 8; ++m) l4[t + m*TPB] = W4[t + m*TPB];
        __syncthreads();
        int wid = __builtin_amdgcn_readfirstlane(t >> 6);
        int row0 = b*32 + wid*4;
        const float* hrow = h + (size_t)row0 * GFIN;    // wave-uniform base
        float acc[4] = {0.f,0.f,0.f,0.f};
        #pragma unroll 8
        for (int k = 0; k < GFIN; ++k) {
            float wv = lds[k*GF + lane];
            #pragma unroll
            for (int q = 0; q < 4; ++q) acc[q] += hrow[q*GFIN + k] * wv;
        }
        float a1 = a[lane], a2 = a[GF + lane];
        #pragma unroll
        for (int q = 0; q < 4; ++q) {
            int row = row0 + q;
            Wh[(size_t)row*GF + lane] = acc[q];
            float v1 = acc[q]*a1, v2 = acc[q]*a2;
            #pragma unroll
            for (int o = 32; o > 0; o >>= 1) { v1 += __shfl_xor(v1, o); v2 += __shfl_xor(v2, o); }
            if (lane == 0) { s1[row] = v1; s2[row] = v2; }
        }
    }
    grid.sync();
    // ================= phase 2: rank-sort s2 (strict order, index tiebreak) ==
    {
        float4* z4 = (float4*)lds;
        const float4* s4 = (const float4*)s2;
        for (int m = t; m < GN/4; m += TPB) z4[m] = s4[m];
        __syncthreads();
        int jl = t >> 4, sl = t & 15;        // 32 j's per block, 16 slices each
        int j = b*32 + jl;
        float zj = lds[j];
        int cnt = 0;
        #pragma unroll 4
        for (int i = 0; i < GN/64; ++i) {    // 128 iters x float4
            int m4 = i*16 + sl;
            float4 v = z4[m4];
            int mb = m4*4;
            cnt += (v.x < zj) || (v.x == zj && mb   < j);
            cnt += (v.y < zj) || (v.y == zj && mb+1 < j);
            cnt += (v.z < zj) || (v.z == zj && mb+2 < j);
            cnt += (v.w < zj) || (v.w == zj && mb+3 < j);
        }
        cnt += __shfl_xor(cnt, 1);
        cnt += __shfl_xor(cnt, 2);
        cnt += __shfl_xor(cnt, 4);
        cnt += __shfl_xor(cnt, 8);
        if (sl == 0) { zs[cnt] = zj; idx[cnt] = j; }
    }
    grid.sync();
    // ================= phase 3: stage zs to LDS; per-chunk totals ============
    {
        float4* z4 = (float4*)lds;
        const float4* g4 = (const float4*)zs;
        for (int m = t; m < GN/4; m += TPB) z4[m] = g4[m];
        __syncthreads();
        float Z = lds[GN-1];
        int wid = __builtin_amdgcn_readfirstlane(t >> 6);
        int ch = b*8 + wid;                  // one chunk (4 elems) per wave
        const int* ip = idx + ch*CHSZ;       // wave-uniform -> s_load
        float aAcc = 0.f, bAcc = 0.f, sa = 0.f, sb = 0.f;
        #pragma unroll
        for (int q = 0; q < CHSZ; ++q) {
            int r = ch*CHSZ + q;
            float zr = lds[r];
            int ir = ip[q];
            float d = zr - Z;
            float tA = __expf(d);
            float tB = __expf(NEG * d);
            float w = Wh[(size_t)ir*GF + lane];
            aAcc += tA*w; bAcc += tB*w; sa += tA; sb += tB;
        }
        chA[ch*GF + lane] = aAcc;
        chB[ch*GF + lane] = bAcc;
        if (lane == 0) { scA[ch] = sa; scB[ch] = sb; }
    }
    grid.sync();
    // ================= phase 4: scans over 2048 chunk totals =================
    // blocks 0..63: channel c; block 64: scalar channels. B: excl prefix; A: excl suffix.
    if (b < 65) {
        float* wred  = lds + 8192;           // above the zs region - no clobber
        float* wredA = lds + 8208;
        int wid = t >> 6;
        int c = b;
        float v[4];
        #pragma unroll
        for (int q = 0; q < 4; ++q) { int ch = t*4 + q; v[q] = (c < 64) ? chB[ch*GF + c] : scB[ch]; }
        float s = v[0]+v[1]+v[2]+v[3];
        float wsc = s;
        #pragma unroll
        for (int o = 1; o < 64; o <<= 1) { float y = __shfl_up(wsc, o); if (lane >= o) wsc += y; }
        if (lane == 63) wred[wid] = wsc;
        __syncthreads();
        float blkoff = 0.f, tot = 0.f;
        #pragma unroll
        for (int w2 = 0; w2 < 8; ++w2) { float x = wred[w2]; tot += x; if (w2 < wid) blkoff += x; }
        float base = blkoff + wsc - s;       // exclusive prefix at chunk 4t
        #pragma unroll
        for (int q = 0; q < 4; ++q) {
            int ch = t*4 + q;
            if (c < 64) ofB[ch*GF + c] = base; else osB[ch] = base;
            base += v[q];
        }
        if (t == 0) { if (c < 64) ofB[NCH*GF + c] = tot; else osB[NCH] = tot; }
        // ---- A: exclusive suffix (reversed exclusive prefix) ----
        #pragma unroll
        for (int q = 0; q < 4; ++q) { int ch = NCH-1 - (t*4 + q); v[q] = (c < 64) ? chA[ch*GF + c] : scA[ch]; }
        s = v[0]+v[1]+v[2]+v[3];
        wsc = s;
        #pragma unroll
        for (int o = 1; o < 64; o <<= 1) { float y = __shfl_up(wsc, o); if (lane >= o) wsc += y; }
        if (lane == 63) wredA[wid] = wsc;
        __syncthreads();
        blkoff = 0.f;
        #pragma unroll
        for (int w2 = 0; w2 < 8; ++w2) { float x = wredA[w2]; if (w2 < wid) blkoff += x; }
        base = blkoff + wsc - s;
        #pragma unroll
        for (int q = 0; q < 4; ++q) {
            int ch = NCH-1 - (t*4 + q);
            if (c < 64) ofA[ch*GF + c] = base; else osA[ch] = base;
            base += v[q];
        }
        if (t == 0) { if (c < 64) ofA[NCH*GF + c] = 0.f; else osA[NCH] = 0.f; }
    }
    grid.sync();
    // ================= phase 5: per-row outputs (4 interleaved rows/wave) ====
    {
        float Z = lds[GN-1];                 // zs still resident in LDS
        int wid = t >> 6;
        int r0 = b*32 + wid*4;
        float s1v[4], g[4], mm[4], aA[4], aB[4];
        int lo[4], hi[4];
        #pragma unroll
        for (int q = 0; q < 4; ++q) {
            s1v[q] = s1[r0 + q]; lo[q] = 0; hi[q] = GN;
            g[q] = s1v[q] + Z;
            mm[q] = (g[q] >= 0.f) ? g[q] : NEG*g[q];   // LeakyReLU(g) = row max
            aA[q] = __expf(g[q] - mm[q]);
            aB[q] = __expf(NEG*g[q] - mm[q]);
        }
        #pragma unroll
        for (int it = 0; it < 13; ++it) {    // 4 independent searches on LDS zs
            #pragma unroll
            for (int q = 0; q < 4; ++q) {
                int mid = (lo[q] + hi[q]) >> 1;
                if (lds[mid] < -s1v[q]) lo[q] = mid + 1; else hi[q] = mid;
            }
        }
        #pragma unroll
        for (int q = 0; q < 4; ++q) {
            int k = lo[q];
            int c0 = __builtin_amdgcn_readfirstlane(k >> 2);   // CHSZ = 4
            float va, vb, sa, pb;
            if (c0 < NCH) {
                va = ofA[c0*GF + lane]; vb = ofB[c0*GF + lane];
                sa = osA[c0];           pb = osB[c0];
                const int* ip = idx + c0*CHSZ;
                #pragma unroll
                for (int qq = 0; qq < CHSZ; ++qq) {
                    int r = c0*CHSZ + qq;
                    float zr = lds[r]; int ir = ip[qq];
                    float w = Wh[(size_t)ir*GF + lane];
                    float d = zr - Z;
                    if (r >= k) { float tA = __expf(d);     va += tA*w; sa += tA; }
                    else        { float tB = __expf(NEG*d); vb += tB*w; pb += tB; }
                }
            } else {                          // k == GN: everything on B side
                va = 0.f; sa = 0.f;
                vb = ofB[NCH*GF + lane]; pb = osB[NCH];
            }
            out[(size_t)(r0+q)*GF + lane] = (aA[q]*va + aB[q]*vb) / (aA[q]*sa + aB[q]*pb);
        }
    }
}

extern "C" void kernel_launch(void* const* d_in, const int* in_sizes, int n_in,
                              void* d_out, int out_size, void* d_ws, size_t ws_size,
                              hipStream_t stream) {
    const float* h = (const float*)d_in[0];
    // d_in[1] = adj (unused by the reference forward)
    const float* W = (const float*)d_in[2];
    const float* a = (const float*)d_in[3];
    float* wsf = (float*)d_ws;
    float* out = (float*)d_out;
    void* args[] = { (void*)&h, (void*)&W, (void*)&a, (void*)&wsf, (void*)&out };
    hipLaunchCooperativeKernel(reinterpret_cast<void*>(k_gat),
                               dim3(NBLK), dim3(TPB), args, 0, stream);
}

// Round 5
// 113.849 us; speedup vs baseline: 1.6285x; 1.6285x over previous
//
#include <hip/hip_runtime.h>
#include <math.h>

#define GN 8192
#define GF 64
#define GFIN 256
#define NEG 0.2f
#define NFINE 256
#define FCH 32      // ranks per fine chunk
#define NCO 32      // coarse chunks (8 fine each)

// workspace layout (floats)
#define OFF_WH   0
#define OFF_S1   (GN*GF)
#define OFF_S2   (OFF_S1 + GN)
#define OFF_ZS   (OFF_S2 + GN)
#define OFF_IDX  (OFF_ZS + GN)              // int32
#define OFF_FA   (OFF_IDX + GN)             // NFINE*GF fine sums, A side
#define OFF_FB   (OFF_FA + NFINE*GF)        // NFINE*GF fine sums, B side
#define OFF_FSA  (OFF_FB + NFINE*GF)        // NFINE scalar sums, A
#define OFF_FSB  (OFF_FSA + NFINE)          // NFINE scalar sums, B
#define ZERO_CNT (2*NFINE*GF + 2*NFINE)

// Kernel 1: Wh = h @ W, s1 = Wh@a1, s2 = Wh@a2. Also zeroes the atomic
// accumulator arrays (workspace is poisoned 0xAA; zeroed EVERY launch so
// replays are self-consistent).
__global__ __launch_bounds__(256) void k_wh(const float* __restrict__ h,
        const float* __restrict__ W, const float* __restrict__ a,
        float* __restrict__ wsf) {
    float* Wh = wsf + OFF_WH;
    float* s1 = wsf + OFF_S1;
    float* s2 = wsf + OFF_S2;
    int t = threadIdx.x, b = blockIdx.x;
    int zm = b*256 + t;                      // 65536 threads cover 33280 slots
    if (zm < ZERO_CNT) wsf[OFF_FA + zm] = 0.f;
    __shared__ float Wl[GFIN*GF];            // 64 KB
    int lane = t & 63;
    const float4* W4 = (const float4*)W;
    float4* Wl4 = (float4*)Wl;
    #pragma unroll
    for (int m = 0; m < 16; ++m) Wl4[t + m*256] = W4[t + m*256];
    __syncthreads();
    int wid = __builtin_amdgcn_readfirstlane(t >> 6);   // SGPR wave id
    int row0 = b*32 + wid*8;
    const float* hrow = h + (size_t)row0 * GFIN;        // wave-uniform base
    float acc[8] = {0.f,0.f,0.f,0.f,0.f,0.f,0.f,0.f};
    #pragma unroll 8
    for (int k = 0; k < GFIN; ++k) {
        float wv = Wl[k*GF + lane];
        #pragma unroll
        for (int q = 0; q < 8; ++q) acc[q] += hrow[q*GFIN + k] * wv;
    }
    float a1 = a[lane], a2 = a[GF + lane];
    #pragma unroll
    for (int q = 0; q < 8; ++q) {
        int row = row0 + q;
        Wh[(size_t)row*GF + lane] = acc[q];
        float v1 = acc[q]*a1, v2 = acc[q]*a2;
        #pragma unroll
        for (int o = 32; o > 0; o >>= 1) { v1 += __shfl_xor(v1, o); v2 += __shfl_xor(v2, o); }
        if (lane == 0) { s1[row] = v1; s2[row] = v2; }
    }
}

// Kernel 2: rank-sort s2 AND scatter fine-chunk partial sums via atomics.
// Each block ranks its 32 j's against all 8192 (LDS b128 sweep), writes the
// sorted (zs, idx), then atomically accumulates tA*Wh[j] / tB*Wh[j] into the
// fine chunk (rank>>5) sums. Z = max(s2) computed in-block.
__global__ __launch_bounds__(512) void k_rank(const float* __restrict__ Whg,
        float* __restrict__ wsf) {
    __shared__ float zl[GN];                 // 32 KB
    __shared__ int rl[32];
    __shared__ float redm[8];
    const float* s2 = wsf + OFF_S2;
    float* zs = wsf + OFF_ZS;
    int* idx = (int*)(wsf + OFF_IDX);
    float* fineA = wsf + OFF_FA;
    float* fineB = wsf + OFF_FB;
    float* fSA = wsf + OFF_FSA;
    float* fSB = wsf + OFF_FSB;
    int t = threadIdx.x, b = blockIdx.x;
    int lane = t & 63, wid = t >> 6;
    // stage s2 to LDS + block max
    const float4* s4 = (const float4*)s2;
    float4* z4 = (float4*)zl;
    float mx = -1e30f;
    for (int m = t; m < GN/4; m += 512) {
        float4 v = s4[m]; z4[m] = v;
        mx = fmaxf(fmaxf(mx, v.x), fmaxf(fmaxf(v.y, v.z), v.w));
    }
    #pragma unroll
    for (int o = 32; o > 0; o >>= 1) mx = fmaxf(mx, __shfl_xor(mx, o));
    if (lane == 0) redm[wid] = mx;
    __syncthreads();
    float Z = redm[0];
    #pragma unroll
    for (int w2 = 1; w2 < 8; ++w2) Z = fmaxf(Z, redm[w2]);
    // rank: 32 j's per block, 16 slices each
    int jl = t >> 4, sl = t & 15;
    int j = b*32 + jl;
    float zj = zl[j];
    int cnt = 0;
    #pragma unroll 4
    for (int i = 0; i < 128; ++i) {
        int m4 = i*16 + sl;
        float4 v = z4[m4];
        int mb = m4*4;
        cnt += (v.x < zj) || (v.x == zj && mb   < j);
        cnt += (v.y < zj) || (v.y == zj && mb+1 < j);
        cnt += (v.z < zj) || (v.z == zj && mb+2 < j);
        cnt += (v.w < zj) || (v.w == zj && mb+3 < j);
    }
    cnt += __shfl_xor(cnt, 1);
    cnt += __shfl_xor(cnt, 2);
    cnt += __shfl_xor(cnt, 4);
    cnt += __shfl_xor(cnt, 8);
    if (sl == 0) { zs[cnt] = zj; idx[cnt] = j; rl[jl] = cnt; }
    __syncthreads();
    // atomic scatter: 8 waves x 4 j's = the block's 32 rows
    #pragma unroll
    for (int q = 0; q < 4; ++q) {
        int jj = wid*4 + q;
        int jg = b*32 + jj;
        int r = rl[jj];
        float zv = zl[jg];
        float d = zv - Z;
        float tA = __expf(d);
        float tB = __expf(NEG*d);
        float w = Whg[(size_t)jg*GF + lane];
        int fc = r >> 5;                     // FCH = 32
        atomicAdd(&fineA[fc*GF + lane], tA*w);
        atomicAdd(&fineB[fc*GF + lane], tB*w);
        if (lane == 0) atomicAdd(&fSA[fc], tA);
        if (lane == 1) atomicAdd(&fSB[fc], tB);
    }
}

// Kernel 3: outputs. Per block (16 rows): build coarse sums from fine, stage
// zs in LDS; per row: LDS binary search -> coarse walk (excl prefix/suffix
// captures) + fine-chunk sums + exact 32-element boundary correction.
__global__ __launch_bounds__(256) void k_out(const float* __restrict__ wsf,
        float* __restrict__ out) {
    __shared__ float zl[GN];                 // 32 KB
    __shared__ float coA[NCO*GF];            // 8 KB
    __shared__ float coB[NCO*GF];            // 8 KB
    __shared__ float cSA[NCO];
    __shared__ float cSB[NCO];
    const float* Wh = wsf + OFF_WH;
    const float* s1 = wsf + OFF_S1;
    const float* zs = wsf + OFF_ZS;
    const int* idx = (const int*)(wsf + OFF_IDX);
    const float* fineA = wsf + OFF_FA;
    const float* fineB = wsf + OFF_FB;
    const float* fSA = wsf + OFF_FSA;
    const float* fSB = wsf + OFF_FSB;
    int t = threadIdx.x, b = blockIdx.x;
    int lane = t & 63, wid = t >> 6;
    // stage zs
    const float4* g4 = (const float4*)zs;
    float4* z4 = (float4*)zl;
    #pragma unroll
    for (int m = 0; m < 8; ++m) z4[t + m*256] = g4[t + m*256];
    // build coarse from fine (each thread: 8 coarse entries of its channel)
    {
        int c = t & 63, g = t >> 6;
        #pragma unroll
        for (int u = 0; u < 8; ++u) {
            int cc = g*8 + u;
            float sa = 0.f, sb = 0.f;
            #pragma unroll
            for (int e = 0; e < 8; ++e) {
                sa += fineA[(cc*8+e)*GF + c];
                sb += fineB[(cc*8+e)*GF + c];
            }
            coA[cc*GF + c] = sa;
            coB[cc*GF + c] = sb;
        }
        if (t < NCO) {
            float sa = 0.f;
            #pragma unroll
            for (int e = 0; e < 8; ++e) sa += fSA[t*8+e];
            cSA[t] = sa;
        } else if (t < 2*NCO) {
            int cc = t - NCO;
            float sb = 0.f;
            #pragma unroll
            for (int e = 0; e < 8; ++e) sb += fSB[cc*8+e];
            cSB[cc] = sb;
        }
    }
    __syncthreads();
    float Z = zl[GN-1];
    int i0 = b*16 + wid*4;
    float s1v[4], aA[4], aB[4];
    #pragma unroll
    for (int q = 0; q < 4; ++q) {
        float s1i = s1[i0 + q];
        s1v[q] = s1i;
        float g = s1i + Z;
        float m = (g >= 0.f) ? g : NEG*g;    // LeakyReLU(g) = row max of e
        aA[q] = __expf(g - m);               // <= 1
        aB[q] = __expf(NEG*g - m);           // <= 1
    }
    int lo[4] = {0,0,0,0}, hi[4] = {GN,GN,GN,GN};
    #pragma unroll
    for (int it = 0; it < 13; ++it) {        // lower_bound: first zl[k] >= -s1
        #pragma unroll
        for (int q = 0; q < 4; ++q) {
            int mid = (lo[q]+hi[q]) >> 1;
            if (zl[mid] < -s1v[q]) lo[q] = mid+1; else hi[q] = mid;
        }
    }
    int kk[4], cco[4], cfi[4];
    #pragma unroll
    for (int q = 0; q < 4; ++q) {
        kk[q] = lo[q];
        cco[q] = min(kk[q] >> 8, NCO-1);
        cfi[q] = min(kk[q] >> 5, NFINE-1);
    }
    float va[4] = {0,0,0,0}, vb[4] = {0,0,0,0};
    float sa[4] = {0,0,0,0}, pb[4] = {0,0,0,0};
    // coarse exclusive prefix (B)
    float runB = 0.f, runSB = 0.f;
    for (int ch = 0; ch < NCO; ++ch) {
        #pragma unroll
        for (int q = 0; q < 4; ++q)
            if (ch == cco[q]) { vb[q] = runB; pb[q] = runSB; }
        runB += coB[ch*GF + lane];
        runSB += cSB[ch];
    }
    // coarse exclusive suffix (A)
    float runA = 0.f, runSA = 0.f;
    for (int ch = NCO-1; ch >= 0; --ch) {
        #pragma unroll
        for (int q = 0; q < 4; ++q)
            if (ch == cco[q]) { va[q] = runA; sa[q] = runSA; }
        runA += coA[ch*GF + lane];
        runSA += cSA[ch];
    }
    // fine level + exact boundary-chunk correction
    #pragma unroll
    for (int q = 0; q < 4; ++q) {
        int fb0 = cco[q]*8;
        #pragma unroll
        for (int e = 0; e < 8; ++e) {
            int fc = fb0 + e;
            float fa = fineA[fc*GF + lane];
            float fb = fineB[fc*GF + lane];
            float fsa = fSA[fc], fsb = fSB[fc];
            if (fc < cfi[q]) { vb[q] += fb; pb[q] += fsb; }
            else if (fc > cfi[q]) { va[q] += fa; sa[q] += fsa; }
        }
        int r0 = cfi[q]*FCH;
        #pragma unroll 8
        for (int e = 0; e < FCH; ++e) {
            int r = r0 + e;
            float zr = zl[r];
            int ir = idx[r];
            float w = Wh[(size_t)ir*GF + lane];
            float d = zr - Z;
            if (r >= kk[q]) { float tA = __expf(d);     va[q] += tA*w; sa[q] += tA; }
            else            { float tB = __expf(NEG*d); vb[q] += tB*w; pb[q] += tB; }
        }
        out[(size_t)(i0+q)*GF + lane] =
            (aA[q]*va[q] + aB[q]*vb[q]) / (aA[q]*sa[q] + aB[q]*pb[q]);
    }
}

extern "C" void kernel_launch(void* const* d_in, const int* in_sizes, int n_in,
                              void* d_out, int out_size, void* d_ws, size_t ws_size,
                              hipStream_t stream) {
    const float* h = (const float*)d_in[0];
    // d_in[1] = adj (unused by the reference forward)
    const float* W = (const float*)d_in[2];
    const float* a = (const float*)d_in[3];
    float* wsf = (float*)d_ws;
    float* out = (float*)d_out;

    hipLaunchKernelGGL(k_wh,   dim3(GN/32), dim3(256), 0, stream, h, W, a, wsf);
    hipLaunchKernelGGL(k_rank, dim3(GN/32), dim3(512), 0, stream, wsf + OFF_WH, wsf);
    hipLaunchKernelGGL(k_out,  dim3(GN/16), dim3(256), 0, stream, wsf, out);
}

// Round 6
// 113.647 us; speedup vs baseline: 1.6314x; 1.0018x over previous
//
#include <hip/hip_runtime.h>
#include <math.h>

#define GN 8192
#define GF 64
#define GFIN 256
#define NEG 0.2f
#define NFINE 256
#define FCH 32      // ranks per fine chunk
#define NCO 32      // coarse chunks (8 fine each, 256 ranks)

// workspace layout (floats)
#define OFF_WH   0
#define OFF_S1   (GN*GF)
#define OFF_S2   (OFF_S1 + GN)
#define OFF_ZS   (OFF_S2 + GN)
#define OFF_IDX  (OFF_ZS + GN)              // int32
#define OFF_FA   (OFF_IDX + GN)             // NFINE*GF fine sums, A side
#define OFF_FB   (OFF_FA + NFINE*GF)        // NFINE*GF fine sums, B side
#define OFF_FSA  (OFF_FB + NFINE*GF)        // NFINE scalar sums, A
#define OFF_FSB  (OFF_FSA + NFINE)          // NFINE scalar sums, B

// Kernel 1: Wh = h @ W, s1 = Wh@a1, s2 = Wh@a2.
// h read via wave-uniform scalar loads; W staged in LDS (2-way alias free).
__global__ __launch_bounds__(256) void k_wh(const float* __restrict__ h,
        const float* __restrict__ W, const float* __restrict__ a,
        float* __restrict__ wsf) {
    float* Wh = wsf + OFF_WH;
    float* s1 = wsf + OFF_S1;
    float* s2 = wsf + OFF_S2;
    __shared__ float Wl[GFIN*GF];            // 64 KB
    int t = threadIdx.x, b = blockIdx.x;
    int lane = t & 63;
    const float4* W4 = (const float4*)W;
    float4* Wl4 = (float4*)Wl;
    #pragma unroll
    for (int m = 0; m < 16; ++m) Wl4[t + m*256] = W4[t + m*256];
    __syncthreads();
    int wid = __builtin_amdgcn_readfirstlane(t >> 6);   // SGPR wave id
    int row0 = b*32 + wid*8;
    const float* hrow = h + (size_t)row0 * GFIN;        // wave-uniform base
    float acc[8] = {0.f,0.f,0.f,0.f,0.f,0.f,0.f,0.f};
    #pragma unroll 8
    for (int k = 0; k < GFIN; ++k) {
        float wv = Wl[k*GF + lane];
        #pragma unroll
        for (int q = 0; q < 8; ++q) acc[q] += hrow[q*GFIN + k] * wv;
    }
    float a1 = a[lane], a2 = a[GF + lane];
    #pragma unroll
    for (int q = 0; q < 8; ++q) {
        int row = row0 + q;
        Wh[(size_t)row*GF + lane] = acc[q];
        float v1 = acc[q]*a1, v2 = acc[q]*a2;
        #pragma unroll
        for (int o = 32; o > 0; o >>= 1) { v1 += __shfl_xor(v1, o); v2 += __shfl_xor(v2, o); }
        if (lane == 0) { s1[row] = v1; s2[row] = v2; }
    }
}

// Kernel 2: rank-sort s2 (strict total order with index tiebreak).
__global__ __launch_bounds__(256) void k_rank(float* __restrict__ wsf) {
    __shared__ float zl[GN];                 // 32 KB
    const float* s2 = wsf + OFF_S2;
    float* zs = wsf + OFF_ZS;
    int* idx = (int*)(wsf + OFF_IDX);
    int t = threadIdx.x, b = blockIdx.x;
    const float4* s4 = (const float4*)s2;
    float4* z4 = (float4*)zl;
    for (int m = t; m < GN/4; m += 256) z4[m] = s4[m];
    __syncthreads();
    int jl = t >> 3, sl = t & 7;             // 32 j's per block, 8 slices each
    int j = b*32 + jl;
    float zj = zl[j];
    int cnt = 0;
    #pragma unroll 4
    for (int i = 0; i < GN/32; ++i) {        // 256 iters x float4
        int m4 = i*8 + sl;
        float4 v = z4[m4];
        int mb = m4*4;
        cnt += (v.x < zj) || (v.x == zj && mb   < j);
        cnt += (v.y < zj) || (v.y == zj && mb+1 < j);
        cnt += (v.z < zj) || (v.z == zj && mb+2 < j);
        cnt += (v.w < zj) || (v.w == zj && mb+3 < j);
    }
    cnt += __shfl_xor(cnt, 1);
    cnt += __shfl_xor(cnt, 2);
    cnt += __shfl_xor(cnt, 4);
    if (sl == 0) { zs[cnt] = zj; idx[cnt] = j; }
}

// Kernel 3: build fine tables race-free by GATHER. Wave = one fine chunk
// (32 consecutive ranks): wave-uniform s_loads of zs/idx, coalesced Wh row
// gathers, each table entry written exactly once. No atomics, no zeroing.
__global__ __launch_bounds__(256) void k_fine(float* __restrict__ wsf) {
    const float* Wh = wsf + OFF_WH;
    const float* zs = wsf + OFF_ZS;
    const int* idx = (const int*)(wsf + OFF_IDX);
    float* fineA = wsf + OFF_FA;
    float* fineB = wsf + OFF_FB;
    float* fSA = wsf + OFF_FSA;
    float* fSB = wsf + OFF_FSB;
    int t = threadIdx.x, lane = t & 63;
    int wid = __builtin_amdgcn_readfirstlane(t >> 6);
    int fc = blockIdx.x*4 + wid;
    float Z = zs[GN-1];
    float aAcc = 0.f, bAcc = 0.f, sa = 0.f, sb = 0.f;
    #pragma unroll 8
    for (int q = 0; q < FCH; ++q) {
        int r = fc*FCH + q;
        float zr = zs[r];                    // wave-uniform -> s_load
        int ir = idx[r];
        float d = zr - Z;
        float tA = __expf(d);
        float tB = __expf(NEG*d);
        float w = Wh[(size_t)ir*GF + lane];
        aAcc += tA*w; bAcc += tB*w; sa += tA; sb += tB;
    }
    fineA[fc*GF + lane] = aAcc;
    fineB[fc*GF + lane] = bAcc;
    if (lane == 0) { fSA[fc] = sa; fSB[fc] = sb; }
}

// Kernel 4: outputs. Per block (16 rows): build coarse sums from fine tables,
// stage zs in LDS; per row: LDS binary search -> coarse walk (excl
// prefix/suffix captures) + fine-chunk sums + exact 32-element boundary fix.
__global__ __launch_bounds__(256) void k_out(const float* __restrict__ wsf,
        float* __restrict__ out) {
    __shared__ float zl[GN];                 // 32 KB
    __shared__ float coA[NCO*GF];            // 8 KB
    __shared__ float coB[NCO*GF];            // 8 KB
    __shared__ float cSA[NCO];
    __shared__ float cSB[NCO];
    const float* Wh = wsf + OFF_WH;
    const float* s1 = wsf + OFF_S1;
    const float* zs = wsf + OFF_ZS;
    const int* idx = (const int*)(wsf + OFF_IDX);
    const float* fineA = wsf + OFF_FA;
    const float* fineB = wsf + OFF_FB;
    const float* fSA = wsf + OFF_FSA;
    const float* fSB = wsf + OFF_FSB;
    int t = threadIdx.x, b = blockIdx.x;
    int lane = t & 63, wid = t >> 6;
    // stage zs
    const float4* g4 = (const float4*)zs;
    float4* z4 = (float4*)zl;
    #pragma unroll
    for (int m = 0; m < 8; ++m) z4[t + m*256] = g4[t + m*256];
    // build coarse from fine (each thread: 8 coarse entries of its channel)
    {
        int c = t & 63, g = t >> 6;
        #pragma unroll
        for (int u = 0; u < 8; ++u) {
            int cc = g*8 + u;
            float sa = 0.f, sb = 0.f;
            #pragma unroll
            for (int e = 0; e < 8; ++e) {
                sa += fineA[(cc*8+e)*GF + c];
                sb += fineB[(cc*8+e)*GF + c];
            }
            coA[cc*GF + c] = sa;
            coB[cc*GF + c] = sb;
        }
        if (t < NCO) {
            float sa = 0.f;
            #pragma unroll
            for (int e = 0; e < 8; ++e) sa += fSA[t*8+e];
            cSA[t] = sa;
        } else if (t < 2*NCO) {
            int cc = t - NCO;
            float sb = 0.f;
            #pragma unroll
            for (int e = 0; e < 8; ++e) sb += fSB[cc*8+e];
            cSB[cc] = sb;
        }
    }
    __syncthreads();
    float Z = zl[GN-1];
    int i0 = b*16 + wid*4;
    float s1v[4], aA[4], aB[4];
    #pragma unroll
    for (int q = 0; q < 4; ++q) {
        float s1i = s1[i0 + q];
        s1v[q] = s1i;
        float g = s1i + Z;
        float m = (g >= 0.f) ? g : NEG*g;    // LeakyReLU(g) = row max of e
        aA[q] = __expf(g - m);               // <= 1
        aB[q] = __expf(NEG*g - m);           // <= 1
    }
    int lo[4] = {0,0,0,0}, hi[4] = {GN,GN,GN,GN};
    #pragma unroll
    for (int it = 0; it < 13; ++it) {        // lower_bound: first zl[k] >= -s1
        #pragma unroll
        for (int q = 0; q < 4; ++q) {
            int mid = (lo[q]+hi[q]) >> 1;
            if (zl[mid] < -s1v[q]) lo[q] = mid+1; else hi[q] = mid;
        }
    }
    int kk[4], cco[4], cfi[4];
    #pragma unroll
    for (int q = 0; q < 4; ++q) {
        kk[q] = lo[q];
        cco[q] = min(kk[q] >> 8, NCO-1);
        cfi[q] = min(kk[q] >> 5, NFINE-1);
    }
    float va[4] = {0,0,0,0}, vb[4] = {0,0,0,0};
    float sa[4] = {0,0,0,0}, pb[4] = {0,0,0,0};
    // coarse exclusive prefix (B)
    float runB = 0.f, runSB = 0.f;
    for (int ch = 0; ch < NCO; ++ch) {
        #pragma unroll
        for (int q = 0; q < 4; ++q)
            if (ch == cco[q]) { vb[q] = runB; pb[q] = runSB; }
        runB += coB[ch*GF + lane];
        runSB += cSB[ch];
    }
    // coarse exclusive suffix (A)
    float runA = 0.f, runSA = 0.f;
    for (int ch = NCO-1; ch >= 0; --ch) {
        #pragma unroll
        for (int q = 0; q < 4; ++q)
            if (ch == cco[q]) { va[q] = runA; sa[q] = runSA; }
        runA += coA[ch*GF + lane];
        runSA += cSA[ch];
    }
    // fine level + exact boundary-chunk correction
    #pragma unroll
    for (int q = 0; q < 4; ++q) {
        int fb0 = cco[q]*8;
        #pragma unroll
        for (int e = 0; e < 8; ++e) {
            int fc = fb0 + e;
            float fa = fineA[fc*GF + lane];
            float fb = fineB[fc*GF + lane];
            float fsa = fSA[fc], fsb = fSB[fc];
            if (fc < cfi[q]) { vb[q] += fb; pb[q] += fsb; }
            else if (fc > cfi[q]) { va[q] += fa; sa[q] += fsa; }
        }
        int r0 = cfi[q]*FCH;
        #pragma unroll 8
        for (int e = 0; e < FCH; ++e) {
            int r = r0 + e;
            float zr = zl[r];
            int ir = idx[r];                 // wave-uniform -> s_load
            float w = Wh[(size_t)ir*GF + lane];
            float d = zr - Z;
            if (r >= kk[q]) { float tA = __expf(d);     va[q] += tA*w; sa[q] += tA; }
            else            { float tB = __expf(NEG*d); vb[q] += tB*w; pb[q] += tB; }
        }
        out[(size_t)(i0+q)*GF + lane] =
            (aA[q]*va[q] + aB[q]*vb[q]) / (aA[q]*sa[q] + aB[q]*pb[q]);
    }
}

extern "C" void kernel_launch(void* const* d_in, const int* in_sizes, int n_in,
                              void* d_out, int out_size, void* d_ws, size_t ws_size,
                              hipStream_t stream) {
    const float* h = (const float*)d_in[0];
    // d_in[1] = adj (unused by the reference forward)
    const float* W = (const float*)d_in[2];
    const float* a = (const float*)d_in[3];
    float* wsf = (float*)d_ws;
    float* out = (float*)d_out;

    hipLaunchKernelGGL(k_wh,   dim3(GN/32),   dim3(256), 0, stream, h, W, a, wsf);
    hipLaunchKernelGGL(k_rank, dim3(GN/32),   dim3(256), 0, stream, wsf);
    hipLaunchKernelGGL(k_fine, dim3(NFINE/4), dim3(256), 0, stream, wsf);
    hipLaunchKernelGGL(k_out,  dim3(GN/16),   dim3(256), 0, stream, wsf, out);
}

// Round 7
// 69.484 us; speedup vs baseline: 2.6683x; 1.6356x over previous
//
#include <hip/hip_runtime.h>
#include <math.h>

#define GN 8192
#define GF 64
#define GFIN 256
#define NEG 0.2f
#define NFINE 256
#define FCH 32      // ranks per fine chunk

// workspace layout (floats)
#define OFF_WH   0
#define OFF_S1   (GN*GF)
#define OFF_S2   (OFF_S1 + GN)
#define OFF_ZS   (OFF_S2 + GN)
#define OFF_IDX  (OFF_ZS + GN)              // int32
#define OFF_OFA  (OFF_IDX + GN)             // NFINE*GF exclusive suffix, A
#define OFF_OFB  (OFF_OFA + NFINE*GF)       // NFINE*GF exclusive prefix, B
#define OFF_OSA  (OFF_OFB + NFINE*GF)       // NFINE scalar, A
#define OFF_OSB  (OFF_OSA + NFINE)          // NFINE scalar, B

// Kernel 1: Wh = h @ W, s1 = Wh@a1, s2 = Wh@a2. 512 threads (8 waves/CU),
// 4 rows/wave. h via wave-uniform s_loads; W staged in LDS.
__global__ __launch_bounds__(512) void k_wh(const float* __restrict__ h,
        const float* __restrict__ W, const float* __restrict__ a,
        float* __restrict__ wsf) {
    float* Wh = wsf + OFF_WH;
    float* s1 = wsf + OFF_S1;
    float* s2 = wsf + OFF_S2;
    __shared__ float Wl[GFIN*GF];            // 64 KB
    int t = threadIdx.x, b = blockIdx.x;
    int lane = t & 63;
    const float4* W4 = (const float4*)W;
    float4* Wl4 = (float4*)Wl;
    #pragma unroll
    for (int m = 0; m < 8; ++m) Wl4[t + m*512] = W4[t + m*512];
    __syncthreads();
    int wid = __builtin_amdgcn_readfirstlane(t >> 6);   // SGPR wave id
    int row0 = b*32 + wid*4;
    const float* hrow = h + (size_t)row0 * GFIN;        // wave-uniform base
    float acc[4] = {0.f,0.f,0.f,0.f};
    #pragma unroll 8
    for (int k = 0; k < GFIN; ++k) {
        float wv = Wl[k*GF + lane];
        #pragma unroll
        for (int q = 0; q < 4; ++q) acc[q] += hrow[q*GFIN + k] * wv;
    }
    float a1 = a[lane], a2 = a[GF + lane];
    #pragma unroll
    for (int q = 0; q < 4; ++q) {
        int row = row0 + q;
        Wh[(size_t)row*GF + lane] = acc[q];
        float v1 = acc[q]*a1, v2 = acc[q]*a2;
        #pragma unroll
        for (int o = 32; o > 0; o >>= 1) { v1 += __shfl_xor(v1, o); v2 += __shfl_xor(v2, o); }
        if (lane == 0) { s1[row] = v1; s2[row] = v2; }
    }
}

// Kernel 2: rank-sort s2 (strict total order with index tiebreak).
// 512 threads: 32 j's per block, 16 slices each (8 waves/CU).
__global__ __launch_bounds__(512) void k_rank(float* __restrict__ wsf) {
    __shared__ float zl[GN];                 // 32 KB
    const float* s2 = wsf + OFF_S2;
    float* zs = wsf + OFF_ZS;
    int* idx = (int*)(wsf + OFF_IDX);
    int t = threadIdx.x, b = blockIdx.x;
    const float4* s4 = (const float4*)s2;
    float4* z4 = (float4*)zl;
    for (int m = t; m < GN/4; m += 512) z4[m] = s4[m];
    __syncthreads();
    int jl = t >> 4, sl = t & 15;
    int j = b*32 + jl;
    float zj = zl[j];
    int cnt = 0;
    #pragma unroll 4
    for (int i = 0; i < GN/64; ++i) {        // 128 iters x float4
        int m4 = i*16 + sl;
        float4 v = z4[m4];
        int mb = m4*4;
        cnt += (v.x < zj) || (v.x == zj && mb   < j);
        cnt += (v.y < zj) || (v.y == zj && mb+1 < j);
        cnt += (v.z < zj) || (v.z == zj && mb+2 < j);
        cnt += (v.w < zj) || (v.w == zj && mb+3 < j);
    }
    cnt += __shfl_xor(cnt, 1);
    cnt += __shfl_xor(cnt, 2);
    cnt += __shfl_xor(cnt, 4);
    cnt += __shfl_xor(cnt, 8);
    if (sl == 0) { zs[cnt] = zj; idx[cnt] = j; }
}

// Kernel 3: per-channel fine sums + in-block scans. Block c (0..63) = channel
// c; block 64 = scalar channels. Thread t owns ranks [32t, 32t+32): gathers
// Wh[idx[r]*64+c], sums tA*w / tB*w, then block-wide exclusive prefix (B) and
// TRUE reversed exclusive suffix (A) via shuffle scan + LDS combine.
__global__ __launch_bounds__(256) void k_colscan(float* __restrict__ wsf) {
    __shared__ float stg[NFINE];             // route fA/fB to reversed threads
    __shared__ float wred[4];
    const float* Wh = wsf + OFF_WH;
    const float* zs = wsf + OFF_ZS;
    const int* idx = (const int*)(wsf + OFF_IDX);
    float* ofA = wsf + OFF_OFA;
    float* ofB = wsf + OFF_OFB;
    float* osA = wsf + OFF_OSA;
    float* osB = wsf + OFF_OSB;
    int c = blockIdx.x;
    int t = threadIdx.x, lane = t & 63, wid = t >> 6;
    float Z = zs[GN-1];
    float fA = 0.f, fB = 0.f;
    #pragma unroll 8
    for (int q = 0; q < FCH; ++q) {
        int r = t*FCH + q;
        float d = zs[r] - Z;
        float tA = __expf(d);
        float tB = __expf(NEG*d);
        float w = (c < 64) ? Wh[(size_t)idx[r]*GF + c] : 1.0f;
        fA += tA*w; fB += tB*w;
    }
    // ---- B: exclusive prefix over chunk index t ----
    {
        float ws = fB;
        #pragma unroll
        for (int o = 1; o < 64; o <<= 1) { float y = __shfl_up(ws, o); if (lane >= o) ws += y; }
        if (lane == 63) wred[wid] = ws;
        __syncthreads();
        float blkoff = 0.f;
        #pragma unroll
        for (int w2 = 0; w2 < 4; ++w2) { float x = wred[w2]; if (w2 < wid) blkoff += x; }
        float exB = blkoff + ws - fB;
        if (c < 64) ofB[t*GF + c] = exB; else osB[t] = exB;
    }
    __syncthreads();
    // ---- A: exclusive suffix = reversed exclusive prefix (true scan) ----
    stg[t] = fA;
    __syncthreads();
    {
        int rt = NFINE-1-t;
        float vA = stg[rt];
        float ws = vA;
        #pragma unroll
        for (int o = 1; o < 64; o <<= 1) { float y = __shfl_up(ws, o); if (lane >= o) ws += y; }
        __syncthreads();                     // wred reuse
        if (lane == 63) wred[wid] = ws;
        __syncthreads();
        float blkoff = 0.f;
        #pragma unroll
        for (int w2 = 0; w2 < 4; ++w2) { float x = wred[w2]; if (w2 < wid) blkoff += x; }
        float exA = blkoff + ws - vA;        // sum over chunks > rt
        if (c < 64) ofA[rt*GF + c] = exA; else osA[rt] = exA;
    }
}

// Kernel 4: per-row output. One wave per row, 2048 blocks (32 waves/CU).
// Global binary search + fine-chunk offsets + exact 32-element boundary fix.
__global__ __launch_bounds__(256) void k_out(const float* __restrict__ wsf,
        float* __restrict__ out) {
    const float* Wh = wsf + OFF_WH;
    const float* s1 = wsf + OFF_S1;
    const float* zs = wsf + OFF_ZS;
    const int* idx = (const int*)(wsf + OFF_IDX);
    const float* ofA = wsf + OFF_OFA;
    const float* ofB = wsf + OFF_OFB;
    const float* osA = wsf + OFF_OSA;
    const float* osB = wsf + OFF_OSB;
    int t = threadIdx.x;
    int wid = t >> 6, lane = t & 63;
    int i = blockIdx.x*4 + wid;
    float s1i = s1[i];
    float Z = zs[GN-1];
    float g = s1i + Z;
    float m = (g >= 0.f) ? g : NEG*g;        // LeakyReLU(g) = row max of e
    float aA = __expf(g - m);                // <= 1
    float aB = __expf(NEG*g - m);            // <= 1
    float tgt = -s1i;
    int lo = 0, hi = GN;                     // lower_bound: first zs[k] >= tgt
    #pragma unroll
    for (int it = 0; it < 13; ++it) {
        int mid = (lo + hi) >> 1;
        if (zs[mid] < tgt) lo = mid + 1; else hi = mid;
    }
    int k = lo;
    int fc = __builtin_amdgcn_readfirstlane(min(k >> 5, NFINE-1));
    float va = ofA[fc*GF + lane];            // sum over chunks > fc (A side)
    float vb = ofB[fc*GF + lane];            // sum over chunks < fc (B side)
    float sa = osA[fc], pb = osB[fc];
    #pragma unroll 8
    for (int q = 0; q < FCH; ++q) {
        int r = fc*FCH + q;
        float zr = zs[r];
        int ir = idx[r];
        float w = Wh[(size_t)ir*GF + lane];
        float d = zr - Z;
        if (r >= k) { float tA = __expf(d);     va += tA*w; sa += tA; }
        else        { float tB = __expf(NEG*d); vb += tB*w; pb += tB; }
    }
    out[(size_t)i*GF + lane] = (aA*va + aB*vb) / (aA*sa + aB*pb);
}

extern "C" void kernel_launch(void* const* d_in, const int* in_sizes, int n_in,
                              void* d_out, int out_size, void* d_ws, size_t ws_size,
                              hipStream_t stream) {
    const float* h = (const float*)d_in[0];
    // d_in[1] = adj (unused by the reference forward)
    const float* W = (const float*)d_in[2];
    const float* a = (const float*)d_in[3];
    float* wsf = (float*)d_ws;
    float* out = (float*)d_out;

    hipLaunchKernelGGL(k_wh,      dim3(GN/32), dim3(512), 0, stream, h, W, a, wsf);
    hipLaunchKernelGGL(k_rank,    dim3(GN/32), dim3(512), 0, stream, wsf);
    hipLaunchKernelGGL(k_colscan, dim3(65),    dim3(256), 0, stream, wsf);
    hipLaunchKernelGGL(k_out,     dim3(GN/4),  dim3(256), 0, stream, wsf, out);
}